// Round 10
// baseline (563.055 us; speedup 1.0000x reference)
//
#include <hip/hip_runtime.h>
#include <stdint.h>

#define NN 50000
#define DEG 16
#define MT 16
#define NBLK ((NN + MT - 1) / MT)   // 3125, exact (50000 = 16*3125)
#define LOG2E 1.4426950408889634f

typedef short bf16x8 __attribute__((ext_vector_type(8)));
typedef float f32x4 __attribute__((ext_vector_type(4)));
typedef unsigned short u16;
typedef unsigned int u32;

static __device__ __forceinline__ u16 f2bf(float f) {
  union { float f; u32 u; } v; v.f = f;
  u32 u = v.u + 0x7FFFu + ((v.u >> 16) & 1u);   // round-to-nearest-even
  return (u16)(u >> 16);
}
static __device__ __forceinline__ float rcp_(float x) {
  return __builtin_amdgcn_rcpf(x);
}
static __device__ __forceinline__ float ex2_(float x) {
  return __builtin_amdgcn_exp2f(x);
}

// ---------------------------------------------------------------------------
// Prep (v7 layout, reverted): bf16-convert x, prepack MFMA B-fragments
// (8-wave layout), bias sums. Gate weights/biases PRE-SCALED by log2e (i,f,o)
// / 2*log2e (g) so the elementwise phase uses raw v_exp_f32 (exp2) directly.
// Gate-weight frag (w<8, g<4, kt<8, lane, j):
//   wpk[(((w*4+g)*8+kt)*64+lane)*8+j] = sc * W[col][k],
//   col = g*128 + w*16 + (lane&15),  k = kt*32 + (lane>>4)*8 + j,
//   W = [w_ih | w_hh] along K.
// ---------------------------------------------------------------------------
__global__ void k_prep(const float* __restrict__ x, u16* __restrict__ xb,
                       const float* __restrict__ wih1, const float* __restrict__ whh1, u16* __restrict__ wpk1,
                       const float* __restrict__ wih2, const float* __restrict__ whh2, u16* __restrict__ wpk2,
                       const float* __restrict__ lr1, const float* __restrict__ ll1, u16* __restrict__ epk1,
                       const float* __restrict__ lr2, const float* __restrict__ ll2, u16* __restrict__ epk2,
                       const float* __restrict__ linw, u16* __restrict__ hpk,
                       const float* __restrict__ bi1, const float* __restrict__ bh1, float* __restrict__ bs1,
                       const float* __restrict__ bi2, const float* __restrict__ bh2, float* __restrict__ bs2) {
  int b = blockIdx.x;
  if (b < 128) {
    const float* wih = (b < 64) ? wih1 : wih2;
    const float* whh = (b < 64) ? whh1 : whh2;
    u16* wpk = (b < 64) ? wpk1 : wpk2;
    int t = (b & 63) * 256 + threadIdx.x;          // 0..16383
    int lane = t & 63, kt = (t >> 6) & 7, g = (t >> 9) & 3, w = (t >> 11) & 7;
    int col = g * 128 + w * 16 + (lane & 15);
    int k0 = kt * 32 + (lane >> 4) * 8;
    float sc = (g == 2) ? 2.f * LOG2E : LOG2E;
#pragma unroll
    for (int j = 0; j < 8; ++j) {
      int k = k0 + j;
      float v = (k < 128) ? wih[col * 128 + k] : whh[col * 128 + k - 128];
      wpk[t * 8 + j] = f2bf(sc * v);
    }
  } else if (b < 160) {
    // epilogue weights: k<128 lin_r (over x), k>=128 lin_l (over h) — unscaled
    const float* lrw = (b < 144) ? lr1 : lr2;
    const float* llw = (b < 144) ? ll1 : ll2;
    u16* epk = (b < 144) ? epk1 : epk2;
    int t = ((b - 128) & 15) * 256 + threadIdx.x;  // 0..4095
    int lane = t & 63, kt = (t >> 6) & 7, w = (t >> 9) & 7;
    int col = w * 16 + (lane & 15);
    int k0 = kt * 32 + (lane >> 4) * 8;
#pragma unroll
    for (int j = 0; j < 8; ++j) {
      int k = k0 + j;
      epk[t * 8 + j] = f2bf(k < 128 ? lrw[col * 128 + k] : llw[col * 128 + k - 128]);
    }
  } else if (b < 164) {
    // head weights [64,128], waves 0..3 — unscaled
    int t = (b - 160) * 256 + threadIdx.x;         // 0..1023
    int lane = t & 63, kt = (t >> 6) & 3, w = (t >> 8) & 3;
    int col = w * 16 + (lane & 15);
    int k0 = kt * 32 + (lane >> 4) * 8;
#pragma unroll
    for (int j = 0; j < 8; ++j) hpk[t * 8 + j] = f2bf(linw[col * 128 + k0 + j]);
  } else if (b < 168) {
    int t = (b - 164) * 256 + threadIdx.x;         // 0..1023
    if (t < 1024) {
      int i = t & 511;
      float sc = ((i >> 7) == 2) ? 2.f * LOG2E : LOG2E;
      if (t < 512) bs1[i] = sc * (bi1[i] + bh1[i]);
      else bs2[i] = sc * (bi2[i] + bh2[i]);
    }
  } else {
    int i = (b - 168) * 256 + threadIdx.x;
    int stride = (gridDim.x - 168) * 256;
    for (; i < NN * 128 / 4; i += stride) {
      float4 v = ((const float4*)x)[i];
      ushort4 o;
      o.x = f2bf(v.x); o.y = f2bf(v.y); o.z = f2bf(v.z); o.w = f2bf(v.w);
      ((ushort4*)xb)[i] = o;
    }
  }
}

// ---------------------------------------------------------------------------
// Fused SAGE-LSTM layer, v10: 512 threads = 8 waves, MT=16 nodes/block.
// KEY CHANGES vs v7 (298us/layer):
//  * x A-fragments load per-lane DIRECTLY from global into regs (the 16x16x32
//    A-frag IS a 16B load at xb[idx*128 + lh*8 + kt*32]). Block's 4KB/step of
//    x rows is L1-resident, so the 8-wave redundancy is L1-served.
//    -> LDS A-traffic halves (only h), no AX buffers, no global_load_lds.
//  * IDXT transposed [d][r]: lanes read consecutive words (v6's 8-way
//    conflict fixed).
//  * x-part(s+1) is REGISTER-ONLY -> runs post-EW, pre-barrier: soaks wave
//    skew and overlaps other waves' EW VALU with MFMA. No manual vmcnt —
//    xf loads are register deps tracked across barriers by the compiler.
//  * s_setprio(1) around MFMA clusters (T5; role diversity now exists).
// Accumulation order per gate unchanged (bias -> x kt0..3 -> h kt4..7):
// bit-identical output. AH swizzle: byte ^= (row&15)<<4. 50000%16==0: no
// bounds guards needed.
// ---------------------------------------------------------------------------

#define XLOAD(DCODE)                                                          \
  do {                                                                        \
    int idx_ = ((DCODE) < DEG) ? IDXT[(DCODE) * 16 + lr] : node0 + lr;        \
    const u16* b_ = xin + (size_t)idx_ * 128 + lh * 8;                        \
    xf[0] = *(const bf16x8*)(b_);                                             \
    xf[1] = *(const bf16x8*)(b_ + 32);                                        \
    xf[2] = *(const bf16x8*)(b_ + 64);                                        \
    xf[3] = *(const bf16x8*)(b_ + 96);                                        \
  } while (0)

#define XPART()                                                               \
  do {                                                                        \
    __builtin_amdgcn_s_setprio(1);                                            \
    _Pragma("unroll") for (int g = 0; g < 4; ++g)                             \
        acc[g] = (f32x4){gb[g], gb[g], gb[g], gb[g]};                         \
    _Pragma("unroll") for (int kt = 0; kt < 4; ++kt)                          \
        _Pragma("unroll") for (int g = 0; g < 4; ++g)                         \
            acc[g] = __builtin_amdgcn_mfma_f32_16x16x32_bf16(xf[kt], wreg[g][kt], acc[g], 0, 0, 0); \
    __builtin_amdgcn_s_setprio(0);                                            \
  } while (0)

#define EBAR()                                                                \
  do {                                                                        \
    asm volatile("s_waitcnt lgkmcnt(0)" ::: "memory");                        \
    __builtin_amdgcn_s_barrier();                                             \
    __builtin_amdgcn_sched_barrier(0);                                        \
  } while (0)

template <int L2>
__global__ __launch_bounds__(512, 2) void k_layer(
    const u16* __restrict__ xin, const int* __restrict__ src,
    const u16* __restrict__ wpk, const float* __restrict__ bsum,
    const u16* __restrict__ epk, const float* __restrict__ linlb,
    u16* __restrict__ hout, const u16* __restrict__ hpk,
    const float* __restrict__ linb, float* __restrict__ dout) {
  __shared__ __align__(16) u16 AH[2][MT * 128];   // 2 x 4 KB
  __shared__ int IDXT[DEG * MT];                  // transposed [d][r], 1 KB

  const int tid = threadIdx.x;
  const int w = tid >> 6, l = tid & 63;
  const int lr = l & 15, lh = l >> 4;
  const int node0 = blockIdx.x * MT;

  // ---- register-resident weight panel: 32 frags = 128 VGPRs, loaded ONCE ----
  bf16x8 wreg[4][8];
#pragma unroll
  for (int g = 0; g < 4; ++g)
#pragma unroll
    for (int kt = 0; kt < 8; ++kt)
      wreg[g][kt] = *(const bf16x8*)(wpk + (size_t)(((w * 4 + g) * 8 + kt) * 64 + l) * 8);

  // transposed neighbor indices: IDXT[d*16 + r] = src[(node0+r)*DEG + d]
  if (tid < MT * DEG) {
    IDXT[(tid & 15) * 16 + (tid >> 4)] = src[node0 * DEG + tid];
  }

  float gb[4];
#pragma unroll
  for (int g = 0; g < 4; ++g) gb[g] = bsum[g * 128 + w * 16 + lr];
  float eb = linlb[w * 16 + lr];
  __syncthreads();  // IDXT ready

  bf16x8 xf[4];
  f32x4 acc[4];
  f32x4 c4 = (f32x4){0.f, 0.f, 0.f, 0.f};

  // prologue: x-frags(0), x-part(0), then prefetch x-frags(1)
  XLOAD(0);
  XPART();
  XLOAD(1);

#pragma unroll 1
  for (int step = 0; step < DEG; ++step) {
    const int cb = step & 1, nb = cb ^ 1;

    // h-part(s): K tiles 4..7 from AH[cb] (h == 0 at step 0)
    if (step) {
      __builtin_amdgcn_s_setprio(1);
#pragma unroll
      for (int kt = 0; kt < 4; ++kt) {
        bf16x8 af = *(const bf16x8*)((const char*)AH[cb] + lr * 256 +
                                     ((kt * 64 + lh * 16) ^ ((lr & 15) << 4)));
#pragma unroll
        for (int g = 0; g < 4; ++g)
          acc[g] = __builtin_amdgcn_mfma_f32_16x16x32_bf16(af, wreg[g][4 + kt], acc[g], 0, 0, 0);
      }
      __builtin_amdgcn_s_setprio(0);
    }

    // LSTM elementwise (exp2 domain); write new h (bf16) into AH[nb]
#pragma unroll
    for (int r = 0; r < 4; ++r) {
      float iv = rcp_(1.f + ex2_(-acc[0][r]));
      float fv = rcp_(1.f + ex2_(-acc[1][r]));
      float gv = 1.f - 2.f * rcp_(1.f + ex2_(acc[2][r]));
      float ov = rcp_(1.f + ex2_(-acc[3][r]));
      float cv = fv * c4[r] + iv * gv;
      c4[r] = cv;
      float th = 1.f - 2.f * rcp_(1.f + ex2_(2.f * LOG2E * cv));
      int row = lh * 4 + r;
      int jj = 2 * (w * 16 + lr);
      *(u16*)((char*)AH[nb] + row * 256 + (jj ^ ((row & 15) << 4))) =
          f2bf(ov * th);
    }

    // x-part(s+1): register-only (xf holds d=s+1) -> pre-barrier skew soak.
    // Then prefetch x-frags(s+2) (d=16 -> own features for the epilogue).
    if (step < DEG - 1) {
      XPART();
      XLOAD(step + 2);
    }

    EBAR();  // lgkmcnt(0) + barrier: AH[nb] handoff; xf loads stay in flight
  }

  // Epilogue: out = lin_r(x_own) + lin_l(h_final) + b, ReLU.
  // xf holds own-x frags (d=16, loaded at step 14); AH[0] holds final h.
  f32x4 eacc = (f32x4){eb, eb, eb, eb};
#pragma unroll
  for (int kt = 0; kt < 4; ++kt) {
    bf16x8 bf = *(const bf16x8*)(epk + (size_t)((w * 8 + kt) * 64 + l) * 8);
    eacc = __builtin_amdgcn_mfma_f32_16x16x32_bf16(xf[kt], bf, eacc, 0, 0, 0);
  }
#pragma unroll
  for (int kt = 0; kt < 4; ++kt) {
    bf16x8 af = *(const bf16x8*)((const char*)AH[0] + lr * 256 +
                                 ((kt * 64 + lh * 16) ^ ((lr & 15) << 4)));
    bf16x8 bf = *(const bf16x8*)(epk + (size_t)((w * 8 + 4 + kt) * 64 + l) * 8);
    eacc = __builtin_amdgcn_mfma_f32_16x16x32_bf16(af, bf, eacc, 0, 0, 0);
  }

  if constexpr (!L2) {
#pragma unroll
    for (int r = 0; r < 4; ++r) {
      int node = node0 + lh * 4 + r;
      float v = fmaxf(eacc[r], 0.f);
      hout[(size_t)node * 128 + w * 16 + lr] = f2bf(v);
    }
  } else {
    // stash relu(h2) into AH[1] (free), then fused 128->64 head (waves 0..3)
#pragma unroll
    for (int r = 0; r < 4; ++r) {
      int row = lh * 4 + r;
      float v = fmaxf(eacc[r], 0.f);
      int jj = 2 * (w * 16 + lr);
      *(u16*)((char*)AH[1] + row * 256 + (jj ^ ((row & 15) << 4))) = f2bf(v);
    }
    __syncthreads();
    if (w < 4) {
      float hb = linb[w * 16 + lr];
      f32x4 hacc = (f32x4){hb, hb, hb, hb};
#pragma unroll
      for (int kt = 0; kt < 4; ++kt) {
        bf16x8 af = *(const bf16x8*)((const char*)AH[1] + lr * 256 +
                                     ((kt * 64 + lh * 16) ^ ((lr & 15) << 4)));
        bf16x8 bf = *(const bf16x8*)(hpk + (size_t)((w * 4 + kt) * 64 + l) * 8);
        hacc = __builtin_amdgcn_mfma_f32_16x16x32_bf16(af, bf, hacc, 0, 0, 0);
      }
#pragma unroll
      for (int r = 0; r < 4; ++r) {
        int node = node0 + lh * 4 + r;
        dout[(size_t)node * 64 + w * 16 + lr] = hacc[r];
      }
    }
  }
}

extern "C" void kernel_launch(void* const* d_in, const int* in_sizes, int n_in,
                              void* d_out, int out_size, void* d_ws, size_t ws_size,
                              hipStream_t stream) {
  const float* x    = (const float*)d_in[0];
  const int*   edge = (const int*)d_in[1];   // src = first N*DEG entries
  const float* wih1 = (const float*)d_in[2];
  const float* whh1 = (const float*)d_in[3];
  const float* bih1 = (const float*)d_in[4];
  const float* bhh1 = (const float*)d_in[5];
  const float* ll1w = (const float*)d_in[6];
  const float* ll1b = (const float*)d_in[7];
  const float* lr1w = (const float*)d_in[8];
  const float* wih2 = (const float*)d_in[9];
  const float* whh2 = (const float*)d_in[10];
  const float* bih2 = (const float*)d_in[11];
  const float* bhh2 = (const float*)d_in[12];
  const float* ll2w = (const float*)d_in[13];
  const float* ll2b = (const float*)d_in[14];
  const float* lr2w = (const float*)d_in[15];
  const float* linw = (const float*)d_in[16];
  const float* linb = (const float*)d_in[17];

  char* ws = (char*)d_ws;
  u16* xb    = (u16*)(ws);                       // 12,800,000 B
  u16* h1b   = (u16*)(ws + 12800000);            // 12,800,000 B
  u16* wpk1  = (u16*)(ws + 25600000);            //    262,144 B
  u16* wpk2  = (u16*)(ws + 25862144);            //    262,144 B
  u16* epk1  = (u16*)(ws + 26124288);            //     65,536 B
  u16* epk2  = (u16*)(ws + 26189824);            //     65,536 B
  u16* hpk   = (u16*)(ws + 26255360);            //     16,384 B
  float* bs1 = (float*)(ws + 26271744);          //      2,048 B
  float* bs2 = (float*)(ws + 26273792);          //      2,048 B

  k_prep<<<1000, 256, 0, stream>>>(x, xb,
                                   wih1, whh1, wpk1, wih2, whh2, wpk2,
                                   lr1w, ll1w, epk1, lr2w, ll2w, epk2,
                                   linw, hpk,
                                   bih1, bhh1, bs1, bih2, bhh2, bs2);
  k_layer<0><<<NBLK, 512, 0, stream>>>(xb, edge, wpk1, bs1, epk1, ll1b,
                                       h1b, nullptr, nullptr, nullptr);
  k_layer<1><<<NBLK, 512, 0, stream>>>(h1b, edge, wpk2, bs2, epk2, ll2b,
                                       nullptr, hpk, linb, (float*)d_out);
}